// Round 1
// baseline (470.893 us; speedup 1.0000x reference)
//
#include <hip/hip_runtime.h>

// MHA forward, MI355X gfx950.
// B=2, L=2048, D=1024, H=16, DK=64. Outputs: y [B,L,D] f32 then A [B,H,L,L] f32.
// Strategy: fp16 MFMA (16x16x32) everywhere, f32 accumulate, two-pass causal
// softmax (recompute QK^T), A written once (537MB = the HBM floor).

typedef _Float16 h8 __attribute__((ext_vector_type(8)));
typedef _Float16 h4 __attribute__((ext_vector_type(4)));
typedef float f4 __attribute__((ext_vector_type(4)));

#define L_SEQ 2048
#define NH 16
#define DKH 64
#define DM 1024

static __device__ __forceinline__ void gload16(const void* g, void* l) {
  __builtin_amdgcn_global_load_lds(
      (const __attribute__((address_space(1))) char*)g,
      (__attribute__((address_space(3))) char*)l, 16, 0, 0);
}

// ---------------- cast f32 -> f16 (vectorized) ----------------
__global__ __launch_bounds__(256) void k_cast(const float* __restrict__ in,
                                              _Float16* __restrict__ out, int n4) {
  int i = blockIdx.x * 256 + threadIdx.x;
  if (i >= n4) return;
  f4 v = ((const f4*)in)[i];
  h4 o = {(_Float16)v[0], (_Float16)v[1], (_Float16)v[2], (_Float16)v[3]};
  ((h4*)out)[i] = o;
}

// ------------- transpose+cast weights: W[k][n] f32 -> Wt[n][k] f16 -------------
__global__ __launch_bounds__(256) void k_wt(const float* w0, const float* w1,
                                            const float* w2, const float* w3,
                                            _Float16* o0, _Float16* o1,
                                            _Float16* o2, _Float16* o3) {
  __shared__ _Float16 tile[64][65];
  const float* W;
  _Float16* O;
  switch (blockIdx.z) {
    case 0: W = w0; O = o0; break;
    case 1: W = w1; O = o1; break;
    case 2: W = w2; O = o2; break;
    default: W = w3; O = o3; break;
  }
  int n0 = blockIdx.x * 64, k0 = blockIdx.y * 64;
  int t = threadIdx.x, c = t & 63, r0 = (t >> 6) * 16;
  for (int i = 0; i < 16; ++i)
    tile[r0 + i][c] = (_Float16)W[(size_t)(k0 + r0 + i) * DM + n0 + c];
  __syncthreads();
  for (int i = 0; i < 16; ++i)
    O[(size_t)(n0 + r0 + i) * DM + k0 + c] = tile[c][r0 + i];
}

// ------------- transpose V: [bh][L][64] -> [bh][64][L] -------------
__global__ __launch_bounds__(256) void k_vt(const _Float16* __restrict__ Vb,
                                            _Float16* __restrict__ Vt) {
  __shared__ _Float16 tile[64][65];
  int blk = blockIdx.x, bh = blk >> 5, l0 = (blk & 31) * 64;
  const _Float16* src = Vb + (size_t)bh * L_SEQ * DKH;
  _Float16* dst = Vt + (size_t)bh * DKH * L_SEQ;
  int t = threadIdx.x, c = t & 63, r0 = (t >> 6) * 16;
  for (int i = 0; i < 16; ++i)
    tile[r0 + i][c] = src[(size_t)(l0 + r0 + i) * DKH + c];
  __syncthreads();
  for (int i = 0; i < 16; ++i)
    dst[(size_t)(r0 + i) * L_SEQ + l0 + c] = tile[c][r0 + i];
}

// ------------- GEMM: C[4096x1024] = A[4096x1024] * Bt[1024x1024]^T -------------
// A row-major [M][K] f16, Bt row-major [N][K] f16 (pre-transposed weight).
// mode 0: write f16 to [B,H,L,64] QKV layout.  mode 1: write f32 row-major.
__global__ __launch_bounds__(256) void k_gemm(const _Float16* __restrict__ A,
                                              const _Float16* __restrict__ B0,
                                              const _Float16* __restrict__ B1,
                                              const _Float16* __restrict__ B2,
                                              void* o0, void* o1, void* o2,
                                              int mode) {
  const _Float16* Bt = blockIdx.z == 0 ? B0 : (blockIdx.z == 1 ? B1 : B2);
  void* out = blockIdx.z == 0 ? o0 : (blockIdx.z == 1 ? o1 : o2);
  __shared__ __align__(16) _Float16 lA[128 * 32];
  __shared__ __align__(16) _Float16 lB[128 * 32];
  int t = threadIdx.x, lane = t & 63, w = t >> 6;
  int l15 = lane & 15, g = lane >> 4;
  int wr = w >> 1, wc = w & 1;
  int m0 = blockIdx.x * 128, n0 = blockIdx.y * 128;
  f4 zed = {0.f, 0.f, 0.f, 0.f};
  f4 acc[4][4];
  for (int i = 0; i < 4; ++i)
    for (int j = 0; j < 4; ++j) acc[i][j] = zed;

  int row = t >> 2, colh = (t & 3) * 8;
  const _Float16* ga = A + (size_t)(m0 + row) * DM + colh;
  const _Float16* gb = Bt + (size_t)(n0 + row) * DM + colh;
  _Float16* la0 = &lA[row * 32 + colh];
  _Float16* la1 = &lA[2048 + row * 32 + colh];
  _Float16* lb0 = &lB[row * 32 + colh];
  _Float16* lb1 = &lB[2048 + row * 32 + colh];

  for (int k0 = 0; k0 < DM; k0 += 32) {
    __syncthreads();
    gload16(ga + k0, la0);
    gload16(ga + (size_t)64 * DM + k0, la1);
    gload16(gb + k0, lb0);
    gload16(gb + (size_t)64 * DM + k0, lb1);
    __syncthreads();
    h8 af[4], bfr[4];
#pragma unroll
    for (int mr = 0; mr < 4; ++mr)
      af[mr] = *(const h8*)&lA[(wr * 64 + mr * 16 + l15) * 32 + g * 8];
#pragma unroll
    for (int nr = 0; nr < 4; ++nr)
      bfr[nr] = *(const h8*)&lB[(wc * 64 + nr * 16 + l15) * 32 + g * 8];
#pragma unroll
    for (int mr = 0; mr < 4; ++mr)
#pragma unroll
      for (int nr = 0; nr < 4; ++nr)
        acc[mr][nr] = __builtin_amdgcn_mfma_f32_16x16x32_f16(af[mr], bfr[nr],
                                                             acc[mr][nr], 0, 0, 0);
  }

  if (mode == 0) {
    _Float16* o = (_Float16*)out;
#pragma unroll
    for (int mr = 0; mr < 4; ++mr)
#pragma unroll
      for (int nr = 0; nr < 4; ++nr) {
        int n = n0 + wc * 64 + nr * 16 + l15;
        int h = n >> 6, dk = n & 63;
#pragma unroll
        for (int r = 0; r < 4; ++r) {
          int m = m0 + wr * 64 + mr * 16 + g * 4 + r;
          int b = m >> 11, l = m & 2047;
          o[(((size_t)b * NH + h) * L_SEQ + l) * DKH + dk] = (_Float16)acc[mr][nr][r];
        }
      }
  } else {
    float* o = (float*)out;
#pragma unroll
    for (int mr = 0; mr < 4; ++mr)
#pragma unroll
      for (int nr = 0; nr < 4; ++nr) {
        int n = n0 + wc * 64 + nr * 16 + l15;
#pragma unroll
        for (int r = 0; r < 4; ++r) {
          int m = m0 + wr * 64 + mr * 16 + g * 4 + r;
          o[(size_t)m * DM + n] = acc[mr][nr][r];
        }
      }
  }
}

// ------------- attention: per block = (bh, 64 q-rows); 4 waves x 16 rows -------------
__global__ __launch_bounds__(256) void k_attn(const _Float16* __restrict__ Qh,
                                              const _Float16* __restrict__ Kh,
                                              const _Float16* __restrict__ Vt,
                                              float* __restrict__ Aout,
                                              _Float16* __restrict__ Oh) {
  __shared__ __align__(16) _Float16 Plds[4][16 * 32];
  int blk = blockIdx.x;
  int qt = 31 - (blk & 31);  // heavy q-tiles first (load balance)
  int bh = blk >> 5;
  int b = bh >> 4, h = bh & 15;
  int t = threadIdx.x, w = t >> 6, lane = t & 63;
  int l15 = lane & 15, g = lane >> 4;
  int q0 = qt * 64 + w * 16;

  const _Float16* Qp = Qh + ((size_t)bh * L_SEQ + q0 + l15) * DKH + g * 8;
  h8 qf0 = *(const h8*)Qp;
  h8 qf1 = *(const h8*)(Qp + 32);
  const _Float16* Kbase = Kh + (size_t)bh * L_SEQ * DKH;
  const _Float16* Vbase = Vt + (size_t)bh * DKH * L_SEQ;
  float* Abase = Aout + (size_t)bh * L_SEQ * L_SEQ;
  int ktEnd = (q0 + 15) >> 4;  // == qt*4 + w
  f4 zed = {0.f, 0.f, 0.f, 0.f};

  // pass 1: per-lane online (m,l) over the lane's column subset, then merge.
  float m_l[4], l_l[4];
#pragma unroll
  for (int r = 0; r < 4; ++r) { m_l[r] = -1e30f; l_l[r] = 0.f; }

  for (int kt = 0; kt <= ktEnd; ++kt) {
    const _Float16* Kp = Kbase + (size_t)(kt * 16 + l15) * DKH + g * 8;
    h8 kf0 = *(const h8*)Kp;
    h8 kf1 = *(const h8*)(Kp + 32);
    f4 s = zed;
    s = __builtin_amdgcn_mfma_f32_16x16x32_f16(qf0, kf0, s, 0, 0, 0);
    s = __builtin_amdgcn_mfma_f32_16x16x32_f16(qf1, kf1, s, 0, 0, 0);
    bool diag = (kt == ktEnd);
    int kc = kt * 16 + l15;
#pragma unroll
    for (int r = 0; r < 4; ++r) {
      float sv = s[r] * 0.125f;
      if (diag && kc > q0 + g * 4 + r) sv = -1e30f;
      float m2 = fmaxf(m_l[r], sv);
      float term = (sv > -1e29f) ? __expf(sv - m2) : 0.f;
      l_l[r] = l_l[r] * __expf(m_l[r] - m2) + term;
      m_l[r] = m2;
    }
  }
#pragma unroll
  for (int r = 0; r < 4; ++r) {
    float m = m_l[r], l = l_l[r];
#pragma unroll
    for (int off = 1; off < 16; off <<= 1) {
      float mo = __shfl_xor(m, off, 64);
      float lo = __shfl_xor(l, off, 64);
      float m2 = fmaxf(m, mo);
      l = l * __expf(m - m2) + lo * __expf(mo - m2);
      m = m2;
    }
    m_l[r] = m;
    l_l[r] = 1.f / l;  // l_l now holds inv_l (each row has >=1 unmasked -> l>=1)
  }

  // pass 2: recompute S, write A, accumulate O = P @ V via LDS re-layout of P.
  f4 oacc[4];
#pragma unroll
  for (int dt = 0; dt < 4; ++dt) oacc[dt] = zed;

  for (int kt = 0; kt <= ktEnd; ++kt) {
    const _Float16* Kp = Kbase + (size_t)(kt * 16 + l15) * DKH + g * 8;
    h8 kf0 = *(const h8*)Kp;
    h8 kf1 = *(const h8*)(Kp + 32);
    f4 s = zed;
    s = __builtin_amdgcn_mfma_f32_16x16x32_f16(qf0, kf0, s, 0, 0, 0);
    s = __builtin_amdgcn_mfma_f32_16x16x32_f16(qf1, kf1, s, 0, 0, 0);
    bool diag = (kt == ktEnd);
    int kc = kt * 16 + l15;
    int hf = kt & 1;
#pragma unroll
    for (int r = 0; r < 4; ++r) {
      float sv = s[r] * 0.125f;
      int qr = q0 + g * 4 + r;
      if (diag && kc > qr) sv = -1e30f;
      float p = __expf(sv - m_l[r]);  // masked: exp(-huge) == 0
      Abase[(size_t)qr * L_SEQ + kc] = p * l_l[r];
      Plds[w][(g * 4 + r) * 32 + hf * 16 + l15] = (_Float16)p;
    }
    if (diag && !hf) {  // odd tile count: zero the unused half of the P chunk
#pragma unroll
      for (int r = 0; r < 4; ++r)
        Plds[w][(g * 4 + r) * 32 + 16 + l15] = (_Float16)0.f;
    }
    if (hf || diag) {
      asm volatile("s_waitcnt lgkmcnt(0)" ::: "memory");
      h8 pf = *(const h8*)&Plds[w][l15 * 32 + g * 8];
      int kc0 = (kt & ~1) * 16;
      const _Float16* Vp = Vbase + (size_t)l15 * L_SEQ + kc0 + g * 8;
#pragma unroll
      for (int dt = 0; dt < 4; ++dt) {
        h8 vf = *(const h8*)(Vp + (size_t)dt * 16 * L_SEQ);
        oacc[dt] = __builtin_amdgcn_mfma_f32_16x16x32_f16(pf, vf, oacc[dt], 0, 0, 0);
      }
    }
  }

  // write O (f16, [B][L][D] layout for the output projection)
#pragma unroll
  for (int dt = 0; dt < 4; ++dt)
#pragma unroll
    for (int r = 0; r < 4; ++r) {
      int qr = q0 + g * 4 + r;
      Oh[((size_t)b * L_SEQ + qr) * DM + h * DKH + dt * 16 + l15] =
          (_Float16)(oacc[dt][r] * l_l[r]);
    }

  // zero-fill the strictly-masked columns (k >= q0+16) with coalesced f4 stores
  int zs = q0 + 16;
  for (int rr = 0; rr < 16; ++rr) {
    float* p = Abase + (size_t)(q0 + rr) * L_SEQ;
    for (int c = zs + lane * 4; c < L_SEQ; c += 256)
      *(f4*)(p + c) = zed;
  }
}

extern "C" void kernel_launch(void* const* d_in, const int* in_sizes, int n_in,
                              void* d_out, int out_size, void* d_ws, size_t ws_size,
                              hipStream_t stream) {
  const float* query = (const float*)d_in[0];
  // d_in[1] = causal mask (constant triu k=1) — recomputed in-kernel, unused.
  const float* Wq = (const float*)d_in[2];
  const float* Wk = (const float*)d_in[3];
  const float* Wv = (const float*)d_in[4];
  const float* Wo = (const float*)d_in[5];

  char* ws = (char*)d_ws;
  _Float16* qh  = (_Float16*)(ws);                      //  8 MB  [4096][1024]
  _Float16* Wtq = (_Float16*)(ws + (8ull  << 20));      //  2 MB  [1024][1024]
  _Float16* Wtk = (_Float16*)(ws + (10ull << 20));
  _Float16* Wtv = (_Float16*)(ws + (12ull << 20));
  _Float16* Wto = (_Float16*)(ws + (14ull << 20));
  _Float16* Qh  = (_Float16*)(ws + (16ull << 20));      //  8 MB  [bh][L][64]
  _Float16* Kh  = (_Float16*)(ws + (24ull << 20));
  _Float16* Vh  = (_Float16*)(ws + (32ull << 20));
  _Float16* Vtr = (_Float16*)(ws + (40ull << 20));      //  8 MB  [bh][64][L]
  _Float16* Oh  = (_Float16*)(ws + (48ull << 20));      //  8 MB  [4096][1024]

  float* y = (float*)d_out;
  float* Afull = y + (size_t)4194304;

  k_cast<<<4096, 256, 0, stream>>>(query, qh, 1048576);
  k_wt<<<dim3(16, 16, 4), 256, 0, stream>>>(Wq, Wk, Wv, Wo, Wtq, Wtk, Wtv, Wto);
  k_gemm<<<dim3(32, 8, 3), 256, 0, stream>>>(qh, Wtq, Wtk, Wtv, Qh, Kh, Vh, 0);
  k_vt<<<1024, 256, 0, stream>>>(Vh, Vtr);
  k_attn<<<1024, 256, 0, stream>>>(Qh, Kh, Vtr, Afull, Oh);
  k_gemm<<<dim3(32, 8, 1), 256, 0, stream>>>(Oh, Wto, Wto, Wto, y, y, y, 1);
}

// Round 2
// 375.931 us; speedup vs baseline: 1.2526x; 1.2526x over previous
//
#include <hip/hip_runtime.h>

// MHA forward, MI355X gfx950.
// B=2, L=2048, D=1024, H=16, DK=64. Outputs: y [B,L,D] f32 then A [B,H,L,L] f32.
// fp16 MFMA, f32 accumulate. Two-pass causal softmax with fixed-offset
// normalization; S^T layout (swapped mfma operands) for float4 A-stores.

typedef _Float16 h8 __attribute__((ext_vector_type(8)));
typedef _Float16 h4 __attribute__((ext_vector_type(4)));
typedef float f4 __attribute__((ext_vector_type(4)));

#define L_SEQ 2048
#define NH 16
#define DKH 64
#define DM 1024

static __device__ __forceinline__ void gload16(const void* g, void* l) {
  __builtin_amdgcn_global_load_lds(
      (const __attribute__((address_space(1))) char*)g,
      (__attribute__((address_space(3))) char*)l, 16, 0, 0);
}

// ---------------- cast f32 -> f16 (vectorized) ----------------
__global__ __launch_bounds__(256) void k_cast(const float* __restrict__ in,
                                              _Float16* __restrict__ out, int n4) {
  int i = blockIdx.x * 256 + threadIdx.x;
  if (i >= n4) return;
  f4 v = ((const f4*)in)[i];
  h4 o = {(_Float16)v[0], (_Float16)v[1], (_Float16)v[2], (_Float16)v[3]};
  ((h4*)out)[i] = o;
}

// ------------- transpose+cast weights: W[k][n] f32 -> Wt[n][k] f16 -------------
__global__ __launch_bounds__(256) void k_wt(const float* w0, const float* w1,
                                            const float* w2, const float* w3,
                                            _Float16* o0, _Float16* o1,
                                            _Float16* o2, _Float16* o3) {
  __shared__ _Float16 tile[64][65];
  const float* W;
  _Float16* O;
  switch (blockIdx.z) {
    case 0: W = w0; O = o0; break;
    case 1: W = w1; O = o1; break;
    case 2: W = w2; O = o2; break;
    default: W = w3; O = o3; break;
  }
  int n0 = blockIdx.x * 64, k0 = blockIdx.y * 64;
  int t = threadIdx.x, c = t & 63, r0 = (t >> 6) * 16;
  for (int i = 0; i < 16; ++i)
    tile[r0 + i][c] = (_Float16)W[(size_t)(k0 + r0 + i) * DM + n0 + c];
  __syncthreads();
  for (int i = 0; i < 16; ++i)
    O[(size_t)(n0 + r0 + i) * DM + k0 + c] = tile[c][r0 + i];
}

// ------------- transpose V: [bh][L][64] -> [bh][64][L] -------------
__global__ __launch_bounds__(256) void k_vt(const _Float16* __restrict__ Vb,
                                            _Float16* __restrict__ Vt) {
  __shared__ _Float16 tile[64][65];
  int blk = blockIdx.x, bh = blk >> 5, l0 = (blk & 31) * 64;
  const _Float16* src = Vb + (size_t)bh * L_SEQ * DKH;
  _Float16* dst = Vt + (size_t)bh * DKH * L_SEQ;
  int t = threadIdx.x, c = t & 63, r0 = (t >> 6) * 16;
  for (int i = 0; i < 16; ++i)
    tile[r0 + i][c] = src[(size_t)(l0 + r0 + i) * DKH + c];
  __syncthreads();
  for (int i = 0; i < 16; ++i)
    dst[(size_t)(r0 + i) * L_SEQ + l0 + c] = tile[c][r0 + i];
}

// ------------- GEMM: C[4096x1024] = A[4096x1024] * Bt[1024x1024]^T -------------
__global__ __launch_bounds__(256) void k_gemm(const _Float16* __restrict__ A,
                                              const _Float16* __restrict__ B0,
                                              const _Float16* __restrict__ B1,
                                              const _Float16* __restrict__ B2,
                                              void* o0, void* o1, void* o2,
                                              int mode) {
  const _Float16* Bt = blockIdx.z == 0 ? B0 : (blockIdx.z == 1 ? B1 : B2);
  void* out = blockIdx.z == 0 ? o0 : (blockIdx.z == 1 ? o1 : o2);
  __shared__ __align__(16) _Float16 lA[128 * 32];
  __shared__ __align__(16) _Float16 lB[128 * 32];
  int t = threadIdx.x, lane = t & 63, w = t >> 6;
  int l15 = lane & 15, g = lane >> 4;
  int wr = w >> 1, wc = w & 1;
  int m0 = blockIdx.x * 128, n0 = blockIdx.y * 128;
  f4 zed = {0.f, 0.f, 0.f, 0.f};
  f4 acc[4][4];
  for (int i = 0; i < 4; ++i)
    for (int j = 0; j < 4; ++j) acc[i][j] = zed;

  int row = t >> 2, colh = (t & 3) * 8;
  const _Float16* ga = A + (size_t)(m0 + row) * DM + colh;
  const _Float16* gb = Bt + (size_t)(n0 + row) * DM + colh;
  _Float16* la0 = &lA[row * 32 + colh];
  _Float16* la1 = &lA[2048 + row * 32 + colh];
  _Float16* lb0 = &lB[row * 32 + colh];
  _Float16* lb1 = &lB[2048 + row * 32 + colh];

  for (int k0 = 0; k0 < DM; k0 += 32) {
    __syncthreads();
    gload16(ga + k0, la0);
    gload16(ga + (size_t)64 * DM + k0, la1);
    gload16(gb + k0, lb0);
    gload16(gb + (size_t)64 * DM + k0, lb1);
    __syncthreads();
    h8 af[4], bfr[4];
#pragma unroll
    for (int mr = 0; mr < 4; ++mr)
      af[mr] = *(const h8*)&lA[(wr * 64 + mr * 16 + l15) * 32 + g * 8];
#pragma unroll
    for (int nr = 0; nr < 4; ++nr)
      bfr[nr] = *(const h8*)&lB[(wc * 64 + nr * 16 + l15) * 32 + g * 8];
#pragma unroll
    for (int mr = 0; mr < 4; ++mr)
#pragma unroll
      for (int nr = 0; nr < 4; ++nr)
        acc[mr][nr] = __builtin_amdgcn_mfma_f32_16x16x32_f16(af[mr], bfr[nr],
                                                             acc[mr][nr], 0, 0, 0);
  }

  if (mode == 0) {
    _Float16* o = (_Float16*)out;
#pragma unroll
    for (int mr = 0; mr < 4; ++mr)
#pragma unroll
      for (int nr = 0; nr < 4; ++nr) {
        int n = n0 + wc * 64 + nr * 16 + l15;
        int h = n >> 6, dk = n & 63;
#pragma unroll
        for (int r = 0; r < 4; ++r) {
          int m = m0 + wr * 64 + mr * 16 + g * 4 + r;
          int b = m >> 11, l = m & 2047;
          o[(((size_t)b * NH + h) * L_SEQ + l) * DKH + dk] = (_Float16)acc[mr][nr][r];
        }
      }
  } else {
    float* o = (float*)out;
#pragma unroll
    for (int mr = 0; mr < 4; ++mr)
#pragma unroll
      for (int nr = 0; nr < 4; ++nr) {
        int n = n0 + wc * 64 + nr * 16 + l15;
#pragma unroll
        for (int r = 0; r < 4; ++r) {
          int m = m0 + wr * 64 + mr * 16 + g * 4 + r;
          o[(size_t)m * DM + n] = acc[mr][nr][r];
        }
      }
  }
}

// ------------- attention -------------
// Block = 4 waves x 16 q-rows = 64 q-rows of one (b,h). Grid 1024:
//   bh = blk & 31  (constant XCD per head: blk%8 == bh%8), qt = 31 - (blk>>5)
//   (heavy q-tiles dispatched first).
// S^T trick: mfma(K_frag, Q_frag) -> lane owns q-row = lane&15, k = g*4+r
//   (4 consecutive k per acc reg) -> float4 A-stores, 2-shfl row reduce.
// Fixed-offset softmax: pass 1 accumulates l0 = sum exp2(s*SC) + plain max;
//   per-row c = max(m-12, 0) applied in pass 2 (exactness: scaling commutes).
__global__ __launch_bounds__(256, 2) void k_attn(const _Float16* __restrict__ Qh,
                                                 const _Float16* __restrict__ Kh,
                                                 const _Float16* __restrict__ Vt,
                                                 float* __restrict__ Aout,
                                                 _Float16* __restrict__ Oh) {
  __shared__ __align__(16) _Float16 Plds[4][1024];  // 2KB per wave
  const int blk = blockIdx.x;
  const int bh = blk & 31;
  const int qt = 31 - (blk >> 5);
  const int b = bh >> 4, h = bh & 15;
  const int t = threadIdx.x, w = t >> 6, lane = t & 63;
  const int l15 = lane & 15, g = lane >> 4;
  const int q0 = qt * 64 + w * 16;
  const int q = q0 + l15;  // this lane's q-row (S^T layout)

  const _Float16* Qp = Qh + ((size_t)bh * L_SEQ + q0 + l15) * DKH + g * 8;
  const h8 qf0 = *(const h8*)Qp;
  const h8 qf1 = *(const h8*)(Qp + 32);
  const _Float16* Kbase = Kh + (size_t)bh * L_SEQ * DKH;
  const _Float16* Vbase = Vt + (size_t)bh * DKH * L_SEQ;
  float* Abase = Aout + (size_t)bh * L_SEQ * L_SEQ;
  char* pbase = (char*)&Plds[w][0];
  const int swz = (l15 & 7) << 4;

  const float SC = 0.125f * 1.44269504089f;  // /sqrt(dk), into exp2 domain
  const int nfull = (q0 + 1) >> 6;  // # fully-unmasked 64-wide k-chunks
  f4 zed = {0.f, 0.f, 0.f, 0.f};

  // ---- pass 1: l0 = sum exp2(s*SC), m = max(s*SC) ----
  float m2 = -1e30f, l0 = 0.f;
  for (int c = 0; c < nfull; ++c) {
    h8 kf0[4], kf1[4];
#pragma unroll
    for (int tt = 0; tt < 4; ++tt) {
      const _Float16* Kp = Kbase + (size_t)(c * 64 + tt * 16 + l15) * DKH + g * 8;
      kf0[tt] = *(const h8*)Kp;
      kf1[tt] = *(const h8*)(Kp + 32);
    }
    f4 s[4];
#pragma unroll
    for (int tt = 0; tt < 4; ++tt) {
      s[tt] = __builtin_amdgcn_mfma_f32_16x16x32_f16(kf0[tt], qf0, zed, 0, 0, 0);
      s[tt] = __builtin_amdgcn_mfma_f32_16x16x32_f16(kf1[tt], qf1, s[tt], 0, 0, 0);
    }
#pragma unroll
    for (int tt = 0; tt < 4; ++tt)
#pragma unroll
      for (int r = 0; r < 4; ++r) {
        float sv = s[tt][r] * SC;
        m2 = fmaxf(m2, sv);
        l0 += __builtin_amdgcn_exp2f(sv);
      }
  }
  {  // diagonal chunk (exactly one: chunk nfull)
    h8 kf0[4], kf1[4];
#pragma unroll
    for (int tt = 0; tt < 4; ++tt) {
      const _Float16* Kp =
          Kbase + (size_t)(nfull * 64 + tt * 16 + l15) * DKH + g * 8;
      kf0[tt] = *(const h8*)Kp;
      kf1[tt] = *(const h8*)(Kp + 32);
    }
    f4 s[4];
#pragma unroll
    for (int tt = 0; tt < 4; ++tt) {
      s[tt] = __builtin_amdgcn_mfma_f32_16x16x32_f16(kf0[tt], qf0, zed, 0, 0, 0);
      s[tt] = __builtin_amdgcn_mfma_f32_16x16x32_f16(kf1[tt], qf1, s[tt], 0, 0, 0);
    }
#pragma unroll
    for (int tt = 0; tt < 4; ++tt) {
      int kbase = nfull * 64 + tt * 16 + g * 4;
#pragma unroll
      for (int r = 0; r < 4; ++r) {
        float sv = (kbase + r <= q) ? s[tt][r] * SC : -1e30f;
        m2 = fmaxf(m2, sv);
        l0 += __builtin_amdgcn_exp2f(sv);  // masked -> exp2(-1e30) = 0
      }
    }
  }
  // reduce over the 4 lanes sharing this q-row (l15, +16, +32, +48)
  m2 = fmaxf(m2, __shfl_xor(m2, 16, 64));
  l0 += __shfl_xor(l0, 16, 64);
  m2 = fmaxf(m2, __shfl_xor(m2, 32, 64));
  l0 += __shfl_xor(l0, 32, 64);
  const float c2 = fmaxf(m2 - 12.f, 0.f);  // f16 guard: P = exp2(sv-c2) <= 4096
  const float invs = __builtin_amdgcn_exp2f(c2) / l0;

  // ---- pass 2: recompute S, write A = exp2(sv-c2)*invs, accumulate O ----
  f4 oacc[4];
#pragma unroll
  for (int dt = 0; dt < 4; ++dt) oacc[dt] = zed;

  for (int cc = 0; cc <= nfull; ++cc) {
    h8 kf0[4], kf1[4];
#pragma unroll
    for (int tt = 0; tt < 4; ++tt) {
      const _Float16* Kp = Kbase + (size_t)(cc * 64 + tt * 16 + l15) * DKH + g * 8;
      kf0[tt] = *(const h8*)Kp;
      kf1[tt] = *(const h8*)(Kp + 32);
    }
    f4 s[4];
#pragma unroll
    for (int tt = 0; tt < 4; ++tt) {
      s[tt] = __builtin_amdgcn_mfma_f32_16x16x32_f16(kf0[tt], qf0, zed, 0, 0, 0);
      s[tt] = __builtin_amdgcn_mfma_f32_16x16x32_f16(kf1[tt], qf1, s[tt], 0, 0, 0);
    }
    const bool dchunk = (cc == nfull);
#pragma unroll
    for (int tt = 0; tt < 4; ++tt) {
      f4 pv;
#pragma unroll
      for (int r = 0; r < 4; ++r) {
        float sv = s[tt][r] * SC - c2;
        if (dchunk && (cc * 64 + tt * 16 + g * 4 + r > q)) sv = -1e30f;
        pv[r] = __builtin_amdgcn_exp2f(sv);
      }
      f4 av = {pv[0] * invs, pv[1] * invs, pv[2] * invs, pv[3] * invs};
      *(f4*)(Abase + (size_t)q * L_SEQ + cc * 64 + tt * 16 + g * 4) = av;
      h4 ph = {(_Float16)pv[0], (_Float16)pv[1], (_Float16)pv[2], (_Float16)pv[3]};
      *(h4*)(pbase + l15 * 128 + ((tt * 32 + g * 8) ^ swz)) = ph;
    }
    asm volatile("s_waitcnt lgkmcnt(0)" ::: "memory");
    __builtin_amdgcn_sched_barrier(0);
#pragma unroll
    for (int ks = 0; ks < 2; ++ks) {
      h8 pf = *(const h8*)(pbase + l15 * 128 + ((ks * 64 + g * 16) ^ swz));
      const _Float16* Vp = Vbase + (size_t)l15 * L_SEQ + cc * 64 + ks * 32 + g * 8;
#pragma unroll
      for (int dt = 0; dt < 4; ++dt) {
        h8 vf = *(const h8*)(Vp + (size_t)dt * 16 * L_SEQ);
        oacc[dt] = __builtin_amdgcn_mfma_f32_16x16x32_f16(pf, vf, oacc[dt], 0, 0, 0);
      }
    }
  }

  // O write (f16, [B][L][D]); O rows live at q = g*4+r here (C-layout), so
  // fetch that row's scale via bpermute.
  float sc[4];
#pragma unroll
  for (int r = 0; r < 4; ++r) sc[r] = __shfl(invs, g * 4 + r, 64);
#pragma unroll
  for (int dt = 0; dt < 4; ++dt)
#pragma unroll
    for (int r = 0; r < 4; ++r) {
      int qr = q0 + g * 4 + r;
      Oh[((size_t)b * L_SEQ + qr) * DM + h * DKH + dt * 16 + l15] =
          (_Float16)(oacc[dt][r] * sc[r]);
    }

  // zero-fill strictly-masked columns beyond the diagonal chunk
  const int zs = (nfull + 1) * 64;
  for (int rr = 0; rr < 16; ++rr) {
    float* p = Abase + (size_t)(q0 + rr) * L_SEQ;
    for (int cz = zs + lane * 4; cz < L_SEQ; cz += 256)
      *(f4*)(p + cz) = zed;
  }
}

extern "C" void kernel_launch(void* const* d_in, const int* in_sizes, int n_in,
                              void* d_out, int out_size, void* d_ws, size_t ws_size,
                              hipStream_t stream) {
  const float* query = (const float*)d_in[0];
  // d_in[1] = causal mask (constant triu k=1) — recomputed in-kernel, unused.
  const float* Wq = (const float*)d_in[2];
  const float* Wk = (const float*)d_in[3];
  const float* Wv = (const float*)d_in[4];
  const float* Wo = (const float*)d_in[5];

  char* ws = (char*)d_ws;
  _Float16* qh  = (_Float16*)(ws);                      //  8 MB  [4096][1024]
  _Float16* Wtq = (_Float16*)(ws + (8ull  << 20));      //  2 MB  [1024][1024]
  _Float16* Wtk = (_Float16*)(ws + (10ull << 20));
  _Float16* Wtv = (_Float16*)(ws + (12ull << 20));
  _Float16* Wto = (_Float16*)(ws + (14ull << 20));
  _Float16* Qh  = (_Float16*)(ws + (16ull << 20));      //  8 MB  [bh][L][64]
  _Float16* Kh  = (_Float16*)(ws + (24ull << 20));
  _Float16* Vh  = (_Float16*)(ws + (32ull << 20));
  _Float16* Vtr = (_Float16*)(ws + (40ull << 20));      //  8 MB  [bh][64][L]
  _Float16* Oh  = (_Float16*)(ws + (48ull << 20));      //  8 MB  [4096][1024]

  float* y = (float*)d_out;
  float* Afull = y + (size_t)4194304;

  k_cast<<<4096, 256, 0, stream>>>(query, qh, 1048576);
  k_wt<<<dim3(16, 16, 4), 256, 0, stream>>>(Wq, Wk, Wv, Wo, Wtq, Wtk, Wtv, Wto);
  k_gemm<<<dim3(32, 8, 3), 256, 0, stream>>>(qh, Wtq, Wtk, Wtv, Qh, Kh, Vh, 0);
  k_vt<<<1024, 256, 0, stream>>>(Vh, Vtr);
  k_attn<<<1024, 256, 0, stream>>>(Qh, Kh, Vtr, Afull, Oh);
  k_gemm<<<dim3(32, 8, 1), 256, 0, stream>>>(Oh, Wto, Wto, Wto, y, y, y, 1);
}

// Round 3
// 286.796 us; speedup vs baseline: 1.6419x; 1.3108x over previous
//
#include <hip/hip_runtime.h>

// MHA forward, MI355X gfx950.
// B=2, L=2048, D=1024, H=16, DK=64. Outputs: y [B,L,D] f32 then A [B,H,L,L] f32.
// fp16 MFMA, f32 accumulate. Two-pass causal softmax with fixed-offset
// normalization; S^T layout (swapped mfma operands) for float4 A-stores.
// Round 3: 32 q-rows per wave (two sub-tiles share K and V fragments),
// early V-issue, setprio around MFMA clusters.

typedef _Float16 h8 __attribute__((ext_vector_type(8)));
typedef _Float16 h4 __attribute__((ext_vector_type(4)));
typedef float f4 __attribute__((ext_vector_type(4)));

#define L_SEQ 2048
#define NH 16
#define DKH 64
#define DM 1024

static __device__ __forceinline__ void gload16(const void* g, void* l) {
  __builtin_amdgcn_global_load_lds(
      (const __attribute__((address_space(1))) char*)g,
      (__attribute__((address_space(3))) char*)l, 16, 0, 0);
}

// ---------------- cast f32 -> f16 (vectorized) ----------------
__global__ __launch_bounds__(256) void k_cast(const float* __restrict__ in,
                                              _Float16* __restrict__ out, int n4) {
  int i = blockIdx.x * 256 + threadIdx.x;
  if (i >= n4) return;
  f4 v = ((const f4*)in)[i];
  h4 o = {(_Float16)v[0], (_Float16)v[1], (_Float16)v[2], (_Float16)v[3]};
  ((h4*)out)[i] = o;
}

// ------------- transpose+cast weights: W[k][n] f32 -> Wt[n][k] f16 -------------
__global__ __launch_bounds__(256) void k_wt(const float* w0, const float* w1,
                                            const float* w2, const float* w3,
                                            _Float16* o0, _Float16* o1,
                                            _Float16* o2, _Float16* o3) {
  __shared__ _Float16 tile[64][65];
  const float* W;
  _Float16* O;
  switch (blockIdx.z) {
    case 0: W = w0; O = o0; break;
    case 1: W = w1; O = o1; break;
    case 2: W = w2; O = o2; break;
    default: W = w3; O = o3; break;
  }
  int n0 = blockIdx.x * 64, k0 = blockIdx.y * 64;
  int t = threadIdx.x, c = t & 63, r0 = (t >> 6) * 16;
  for (int i = 0; i < 16; ++i)
    tile[r0 + i][c] = (_Float16)W[(size_t)(k0 + r0 + i) * DM + n0 + c];
  __syncthreads();
  for (int i = 0; i < 16; ++i)
    O[(size_t)(n0 + r0 + i) * DM + k0 + c] = tile[c][r0 + i];
}

// ------------- transpose V: [bh][L][64] -> [bh][64][L] -------------
__global__ __launch_bounds__(256) void k_vt(const _Float16* __restrict__ Vb,
                                            _Float16* __restrict__ Vt) {
  __shared__ _Float16 tile[64][65];
  int blk = blockIdx.x, bh = blk >> 5, l0 = (blk & 31) * 64;
  const _Float16* src = Vb + (size_t)bh * L_SEQ * DKH;
  _Float16* dst = Vt + (size_t)bh * DKH * L_SEQ;
  int t = threadIdx.x, c = t & 63, r0 = (t >> 6) * 16;
  for (int i = 0; i < 16; ++i)
    tile[r0 + i][c] = src[(size_t)(l0 + r0 + i) * DKH + c];
  __syncthreads();
  for (int i = 0; i < 16; ++i)
    dst[(size_t)(r0 + i) * L_SEQ + l0 + c] = tile[c][r0 + i];
}

// ------------- GEMM: C[4096x1024] = A[4096x1024] * Bt[1024x1024]^T -------------
__global__ __launch_bounds__(256) void k_gemm(const _Float16* __restrict__ A,
                                              const _Float16* __restrict__ B0,
                                              const _Float16* __restrict__ B1,
                                              const _Float16* __restrict__ B2,
                                              void* o0, void* o1, void* o2,
                                              int mode) {
  const _Float16* Bt = blockIdx.z == 0 ? B0 : (blockIdx.z == 1 ? B1 : B2);
  void* out = blockIdx.z == 0 ? o0 : (blockIdx.z == 1 ? o1 : o2);
  __shared__ __align__(16) _Float16 lA[128 * 32];
  __shared__ __align__(16) _Float16 lB[128 * 32];
  int t = threadIdx.x, lane = t & 63, w = t >> 6;
  int l15 = lane & 15, g = lane >> 4;
  int wr = w >> 1, wc = w & 1;
  int m0 = blockIdx.x * 128, n0 = blockIdx.y * 128;
  f4 zed = {0.f, 0.f, 0.f, 0.f};
  f4 acc[4][4];
  for (int i = 0; i < 4; ++i)
    for (int j = 0; j < 4; ++j) acc[i][j] = zed;

  int row = t >> 2, colh = (t & 3) * 8;
  const _Float16* ga = A + (size_t)(m0 + row) * DM + colh;
  const _Float16* gb = Bt + (size_t)(n0 + row) * DM + colh;
  _Float16* la0 = &lA[row * 32 + colh];
  _Float16* la1 = &lA[2048 + row * 32 + colh];
  _Float16* lb0 = &lB[row * 32 + colh];
  _Float16* lb1 = &lB[2048 + row * 32 + colh];

  for (int k0 = 0; k0 < DM; k0 += 32) {
    __syncthreads();
    gload16(ga + k0, la0);
    gload16(ga + (size_t)64 * DM + k0, la1);
    gload16(gb + k0, lb0);
    gload16(gb + (size_t)64 * DM + k0, lb1);
    __syncthreads();
    h8 af[4], bfr[4];
#pragma unroll
    for (int mr = 0; mr < 4; ++mr)
      af[mr] = *(const h8*)&lA[(wr * 64 + mr * 16 + l15) * 32 + g * 8];
#pragma unroll
    for (int nr = 0; nr < 4; ++nr)
      bfr[nr] = *(const h8*)&lB[(wc * 64 + nr * 16 + l15) * 32 + g * 8];
#pragma unroll
    for (int mr = 0; mr < 4; ++mr)
#pragma unroll
      for (int nr = 0; nr < 4; ++nr)
        acc[mr][nr] = __builtin_amdgcn_mfma_f32_16x16x32_f16(af[mr], bfr[nr],
                                                             acc[mr][nr], 0, 0, 0);
  }

  if (mode == 0) {
    _Float16* o = (_Float16*)out;
#pragma unroll
    for (int mr = 0; mr < 4; ++mr)
#pragma unroll
      for (int nr = 0; nr < 4; ++nr) {
        int n = n0 + wc * 64 + nr * 16 + l15;
        int h = n >> 6, dk = n & 63;
#pragma unroll
        for (int r = 0; r < 4; ++r) {
          int m = m0 + wr * 64 + mr * 16 + g * 4 + r;
          int b = m >> 11, l = m & 2047;
          o[(((size_t)b * NH + h) * L_SEQ + l) * DKH + dk] = (_Float16)acc[mr][nr][r];
        }
      }
  } else {
    float* o = (float*)out;
#pragma unroll
    for (int mr = 0; mr < 4; ++mr)
#pragma unroll
      for (int nr = 0; nr < 4; ++nr) {
        int n = n0 + wc * 64 + nr * 16 + l15;
#pragma unroll
        for (int r = 0; r < 4; ++r) {
          int m = m0 + wr * 64 + mr * 16 + g * 4 + r;
          o[(size_t)m * DM + n] = acc[mr][nr][r];
        }
      }
  }
}

// ------------- attention -------------
// Block = 4 waves; each wave owns 32 q-rows (two 16-row S^T sub-tiles a/b that
// SHARE the K fragments in QK^T and the V fragments in PV). Block covers 128
// q-rows. Grid 512 = 32 bh x 16 qt; bh = blk & 31 (constant XCD per head),
// qt = 15 - (blk >> 5) (heavy tiles dispatched first).
// S^T trick: mfma(K_frag, Q_frag) -> lane owns q-row = lane&15, k = g*4+r
//   (4 consecutive k per acc reg) -> float4 A-stores, 2-shfl row reduce.
// Fixed-offset softmax: pass 1 accumulates l0 = sum exp2(s*SC) + plain max;
//   per-row c = max(m-12, 0) applied in pass 2 (exactness: scaling commutes).
__global__ __launch_bounds__(256, 2) void k_attn(const _Float16* __restrict__ Qh,
                                                 const _Float16* __restrict__ Kh,
                                                 const _Float16* __restrict__ Vt,
                                                 float* __restrict__ Aout,
                                                 _Float16* __restrict__ Oh) {
  __shared__ __align__(16) _Float16 Plds[4][2][1024];  // 2KB per wave per sub-tile
  const int blk = blockIdx.x;
  const int bh = blk & 31;
  const int qt = 15 - (blk >> 5);
  const int b = bh >> 4, h = bh & 15;
  const int t = threadIdx.x, w = t >> 6, lane = t & 63;
  const int l15 = lane & 15, g = lane >> 4;
  const int q0 = qt * 128 + w * 32;  // wave's rows: q0 .. q0+31
  const int qa = q0 + l15;           // sub-tile a row (S^T layout)
  const int qb = q0 + 16 + l15;      // sub-tile b row

  const _Float16* Qp = Qh + ((size_t)bh * L_SEQ + qa) * DKH + g * 8;
  const h8 qa0 = *(const h8*)Qp;
  const h8 qa1 = *(const h8*)(Qp + 32);
  const h8 qb0 = *(const h8*)(Qp + 16 * DKH);
  const h8 qb1 = *(const h8*)(Qp + 16 * DKH + 32);
  const _Float16* Kbase = Kh + (size_t)bh * L_SEQ * DKH;
  const _Float16* Vbase = Vt + (size_t)bh * DKH * L_SEQ;
  float* Abase = Aout + (size_t)bh * L_SEQ * L_SEQ;
  char* pA = (char*)&Plds[w][0][0];
  char* pB = (char*)&Plds[w][1][0];
  const int swz = (l15 & 7) << 4;

  const float SC = 0.125f * 1.44269504089f;  // /sqrt(dk), into exp2 domain
  const int nfull = q0 >> 6;  // chunks 0..nfull-1 fully unmasked; nfull = diagonal
  f4 zed = {0.f, 0.f, 0.f, 0.f};

  // ---- pass 1: per-row l0 = sum exp2(s*SC), m = max(s*SC) ----
  float mA = -1e30f, sumA = 0.f, mB = -1e30f, sumB = 0.f;
  for (int c = 0; c < nfull; ++c) {
    const _Float16* Kp = Kbase + (size_t)(c * 64 + l15) * DKH + g * 8;
    h8 kf0[4], kf1[4];
#pragma unroll
    for (int tt = 0; tt < 4; ++tt) {
      kf0[tt] = *(const h8*)(Kp + (size_t)tt * 16 * DKH);
      kf1[tt] = *(const h8*)(Kp + (size_t)tt * 16 * DKH + 32);
    }
    f4 sa[4], sb[4];
    __builtin_amdgcn_s_setprio(1);
#pragma unroll
    for (int tt = 0; tt < 4; ++tt) {
      sa[tt] = __builtin_amdgcn_mfma_f32_16x16x32_f16(kf0[tt], qa0, zed, 0, 0, 0);
      sa[tt] = __builtin_amdgcn_mfma_f32_16x16x32_f16(kf1[tt], qa1, sa[tt], 0, 0, 0);
      sb[tt] = __builtin_amdgcn_mfma_f32_16x16x32_f16(kf0[tt], qb0, zed, 0, 0, 0);
      sb[tt] = __builtin_amdgcn_mfma_f32_16x16x32_f16(kf1[tt], qb1, sb[tt], 0, 0, 0);
    }
    __builtin_amdgcn_s_setprio(0);
#pragma unroll
    for (int tt = 0; tt < 4; ++tt)
#pragma unroll
      for (int r = 0; r < 4; ++r) {
        float va = sa[tt][r] * SC, vb = sb[tt][r] * SC;
        mA = fmaxf(mA, va);
        sumA += __builtin_amdgcn_exp2f(va);
        mB = fmaxf(mB, vb);
        sumB += __builtin_amdgcn_exp2f(vb);
      }
  }
  {  // diagonal chunk (chunk index nfull), causal-masked
    const _Float16* Kp = Kbase + (size_t)(nfull * 64 + l15) * DKH + g * 8;
    h8 kf0[4], kf1[4];
#pragma unroll
    for (int tt = 0; tt < 4; ++tt) {
      kf0[tt] = *(const h8*)(Kp + (size_t)tt * 16 * DKH);
      kf1[tt] = *(const h8*)(Kp + (size_t)tt * 16 * DKH + 32);
    }
    f4 sa[4], sb[4];
    __builtin_amdgcn_s_setprio(1);
#pragma unroll
    for (int tt = 0; tt < 4; ++tt) {
      sa[tt] = __builtin_amdgcn_mfma_f32_16x16x32_f16(kf0[tt], qa0, zed, 0, 0, 0);
      sa[tt] = __builtin_amdgcn_mfma_f32_16x16x32_f16(kf1[tt], qa1, sa[tt], 0, 0, 0);
      sb[tt] = __builtin_amdgcn_mfma_f32_16x16x32_f16(kf0[tt], qb0, zed, 0, 0, 0);
      sb[tt] = __builtin_amdgcn_mfma_f32_16x16x32_f16(kf1[tt], qb1, sb[tt], 0, 0, 0);
    }
    __builtin_amdgcn_s_setprio(0);
#pragma unroll
    for (int tt = 0; tt < 4; ++tt) {
      int kb = nfull * 64 + tt * 16 + g * 4;
#pragma unroll
      for (int r = 0; r < 4; ++r) {
        float va = (kb + r <= qa) ? sa[tt][r] * SC : -1e30f;
        float vb = (kb + r <= qb) ? sb[tt][r] * SC : -1e30f;
        mA = fmaxf(mA, va);
        sumA += __builtin_amdgcn_exp2f(va);  // masked -> 0
        mB = fmaxf(mB, vb);
        sumB += __builtin_amdgcn_exp2f(vb);
      }
    }
  }
  // reduce over the 4 lanes sharing each q-row (l15, +16, +32, +48)
  mA = fmaxf(mA, __shfl_xor(mA, 16, 64));
  sumA += __shfl_xor(sumA, 16, 64);
  mA = fmaxf(mA, __shfl_xor(mA, 32, 64));
  sumA += __shfl_xor(sumA, 32, 64);
  mB = fmaxf(mB, __shfl_xor(mB, 16, 64));
  sumB += __shfl_xor(sumB, 16, 64);
  mB = fmaxf(mB, __shfl_xor(mB, 32, 64));
  sumB += __shfl_xor(sumB, 32, 64);
  const float cA = fmaxf(mA - 12.f, 0.f);  // f16 guard: P = exp2(sv-c) <= 4096
  const float cB = fmaxf(mB - 12.f, 0.f);
  const float invA = __builtin_amdgcn_exp2f(cA) / sumA;
  const float invB = __builtin_amdgcn_exp2f(cB) / sumB;

  // ---- pass 2: recompute S, write A = exp2(sv-c)*inv, accumulate O ----
  f4 oaccA[4], oaccB[4];
#pragma unroll
  for (int dt = 0; dt < 4; ++dt) { oaccA[dt] = zed; oaccB[dt] = zed; }

  for (int cc = 0; cc <= nfull; ++cc) {
    // K loads first (QK waits on these), then V (consumed after softmax)
    const _Float16* Kp = Kbase + (size_t)(cc * 64 + l15) * DKH + g * 8;
    h8 kf0[4], kf1[4];
#pragma unroll
    for (int tt = 0; tt < 4; ++tt) {
      kf0[tt] = *(const h8*)(Kp + (size_t)tt * 16 * DKH);
      kf1[tt] = *(const h8*)(Kp + (size_t)tt * 16 * DKH + 32);
    }
    const _Float16* Vp = Vbase + (size_t)l15 * L_SEQ + cc * 64 + g * 8;
    h8 vf[8];
#pragma unroll
    for (int ks = 0; ks < 2; ++ks)
#pragma unroll
      for (int dt = 0; dt < 4; ++dt)
        vf[ks * 4 + dt] = *(const h8*)(Vp + (size_t)dt * 16 * L_SEQ + ks * 32);

    f4 sa[4], sb[4];
    __builtin_amdgcn_s_setprio(1);
#pragma unroll
    for (int tt = 0; tt < 4; ++tt) {
      sa[tt] = __builtin_amdgcn_mfma_f32_16x16x32_f16(kf0[tt], qa0, zed, 0, 0, 0);
      sa[tt] = __builtin_amdgcn_mfma_f32_16x16x32_f16(kf1[tt], qa1, sa[tt], 0, 0, 0);
      sb[tt] = __builtin_amdgcn_mfma_f32_16x16x32_f16(kf0[tt], qb0, zed, 0, 0, 0);
      sb[tt] = __builtin_amdgcn_mfma_f32_16x16x32_f16(kf1[tt], qb1, sb[tt], 0, 0, 0);
    }
    __builtin_amdgcn_s_setprio(0);

    const bool dchunk = (cc == nfull);
    float* ArowA = Abase + (size_t)qa * L_SEQ + cc * 64 + g * 4;
    float* ArowB = Abase + (size_t)qb * L_SEQ + cc * 64 + g * 4;
#pragma unroll
    for (int tt = 0; tt < 4; ++tt) {
      f4 pv;
#pragma unroll
      for (int r = 0; r < 4; ++r) {
        float sv = sa[tt][r] * SC - cA;
        if (dchunk && (cc * 64 + tt * 16 + g * 4 + r > qa)) sv = -1e30f;
        pv[r] = __builtin_amdgcn_exp2f(sv);
      }
      f4 av = {pv[0] * invA, pv[1] * invA, pv[2] * invA, pv[3] * invA};
      *(f4*)(ArowA + tt * 16) = av;
      h4 ph = {(_Float16)pv[0], (_Float16)pv[1], (_Float16)pv[2], (_Float16)pv[3]};
      *(h4*)(pA + l15 * 128 + ((tt * 32 + g * 8) ^ swz)) = ph;
    }
#pragma unroll
    for (int tt = 0; tt < 4; ++tt) {
      f4 pv;
#pragma unroll
      for (int r = 0; r < 4; ++r) {
        float sv = sb[tt][r] * SC - cB;
        if (dchunk && (cc * 64 + tt * 16 + g * 4 + r > qb)) sv = -1e30f;
        pv[r] = __builtin_amdgcn_exp2f(sv);
      }
      f4 av = {pv[0] * invB, pv[1] * invB, pv[2] * invB, pv[3] * invB};
      *(f4*)(ArowB + tt * 16) = av;
      h4 ph = {(_Float16)pv[0], (_Float16)pv[1], (_Float16)pv[2], (_Float16)pv[3]};
      *(h4*)(pB + l15 * 128 + ((tt * 32 + g * 8) ^ swz)) = ph;
    }
    asm volatile("s_waitcnt lgkmcnt(0)" ::: "memory");
    __builtin_amdgcn_sched_barrier(0);
    __builtin_amdgcn_s_setprio(1);
#pragma unroll
    for (int ks = 0; ks < 2; ++ks) {
      h8 pfa = *(const h8*)(pA + l15 * 128 + ((ks * 64 + g * 16) ^ swz));
      h8 pfb = *(const h8*)(pB + l15 * 128 + ((ks * 64 + g * 16) ^ swz));
#pragma unroll
      for (int dt = 0; dt < 4; ++dt) {
        oaccA[dt] = __builtin_amdgcn_mfma_f32_16x16x32_f16(pfa, vf[ks * 4 + dt],
                                                           oaccA[dt], 0, 0, 0);
        oaccB[dt] = __builtin_amdgcn_mfma_f32_16x16x32_f16(pfb, vf[ks * 4 + dt],
                                                           oaccB[dt], 0, 0, 0);
      }
    }
    __builtin_amdgcn_s_setprio(0);
  }

  // O write (f16, [B][L][D]); O rows live at q = g*4+r (C-layout), so fetch
  // that row's scale from the lane that owns it (lane g*4+r has l15 == g*4+r).
  float scA[4], scB[4];
#pragma unroll
  for (int r = 0; r < 4; ++r) {
    scA[r] = __shfl(invA, g * 4 + r, 64);
    scB[r] = __shfl(invB, g * 4 + r, 64);
  }
#pragma unroll
  for (int dt = 0; dt < 4; ++dt)
#pragma unroll
    for (int r = 0; r < 4; ++r) {
      int qra = q0 + g * 4 + r;
      Oh[((size_t)b * L_SEQ + qra) * DM + h * DKH + dt * 16 + l15] =
          (_Float16)(oaccA[dt][r] * scA[r]);
      Oh[((size_t)b * L_SEQ + qra + 16) * DM + h * DKH + dt * 16 + l15] =
          (_Float16)(oaccB[dt][r] * scB[r]);
    }

  // zero-fill strictly-masked columns beyond the diagonal chunk
  const int zs = (nfull + 1) * 64;
  for (int rr = 0; rr < 32; ++rr) {
    float* p = Abase + (size_t)(q0 + rr) * L_SEQ;
    for (int cz = zs + lane * 4; cz < L_SEQ; cz += 256)
      *(f4*)(p + cz) = zed;
  }
}

extern "C" void kernel_launch(void* const* d_in, const int* in_sizes, int n_in,
                              void* d_out, int out_size, void* d_ws, size_t ws_size,
                              hipStream_t stream) {
  const float* query = (const float*)d_in[0];
  // d_in[1] = causal mask (constant triu k=1) — recomputed in-kernel, unused.
  const float* Wq = (const float*)d_in[2];
  const float* Wk = (const float*)d_in[3];
  const float* Wv = (const float*)d_in[4];
  const float* Wo = (const float*)d_in[5];

  char* ws = (char*)d_ws;
  _Float16* qh  = (_Float16*)(ws);                      //  8 MB  [4096][1024]
  _Float16* Wtq = (_Float16*)(ws + (8ull  << 20));      //  2 MB  [1024][1024]
  _Float16* Wtk = (_Float16*)(ws + (10ull << 20));
  _Float16* Wtv = (_Float16*)(ws + (12ull << 20));
  _Float16* Wto = (_Float16*)(ws + (14ull << 20));
  _Float16* Qh  = (_Float16*)(ws + (16ull << 20));      //  8 MB  [bh][L][64]
  _Float16* Kh  = (_Float16*)(ws + (24ull << 20));
  _Float16* Vh  = (_Float16*)(ws + (32ull << 20));
  _Float16* Vtr = (_Float16*)(ws + (40ull << 20));      //  8 MB  [bh][64][L]
  _Float16* Oh  = (_Float16*)(ws + (48ull << 20));      //  8 MB  [4096][1024]

  float* y = (float*)d_out;
  float* Afull = y + (size_t)4194304;

  k_cast<<<4096, 256, 0, stream>>>(query, qh, 1048576);
  k_wt<<<dim3(16, 16, 4), 256, 0, stream>>>(Wq, Wk, Wv, Wo, Wtq, Wtk, Wtv, Wto);
  k_gemm<<<dim3(32, 8, 3), 256, 0, stream>>>(qh, Wtq, Wtk, Wtv, Qh, Kh, Vh, 0);
  k_vt<<<1024, 256, 0, stream>>>(Vh, Vtr);
  k_attn<<<512, 256, 0, stream>>>(Qh, Kh, Vtr, Afull, Oh);
  k_gemm<<<dim3(32, 8, 1), 256, 0, stream>>>(Oh, Wto, Wto, Wto, y, y, y, 1);
}